// Round 8
// baseline (262.745 us; speedup 1.0000x reference)
//
#include <hip/hip_runtime.h>
#include <hip/hip_bf16.h>
#include <math.h>

#define S_  2048
#define DM_ 1024

typedef unsigned short u16;
typedef __attribute__((ext_vector_type(8))) short short8;
typedef __attribute__((ext_vector_type(4))) float f32x4;

__device__ __forceinline__ u16 f2bf(float f) {
  unsigned u = __float_as_uint(f);
  u += 0x7fffu + ((u >> 16) & 1u);           // RNE
  return (u16)(u >> 16);
}
__device__ __forceinline__ float bf2f(u16 h) {
  return __uint_as_float((unsigned)h << 16);
}
__device__ __forceinline__ unsigned pack_bf2(float a, float b) {
  union { __hip_bfloat162 h2; unsigned u; } cv;
  cv.h2 = __float22bfloat162_rn(float2{a, b});   // v_cvt_pk_bf16_f32 on gfx950
  return cv.u;
}
// async global->LDS, 16B per lane. LDS dest is wave-uniform base + lane*16.
__device__ __forceinline__ void cp16(const void* g, void* l) {
  __builtin_amdgcn_global_load_lds(
      (const __attribute__((address_space(1))) unsigned*)(uintptr_t)g,
      (__attribute__((address_space(3))) unsigned*)(unsigned)(uintptr_t)l, 16, 0, 0);
}

// ---------------- fp32 -> bf16 cast ----------------
struct CastArgs { const float* src[5]; u16* dst[5]; int n[5]; };

__global__ __launch_bounds__(256) void cast_kernel(CastArgs a) {
  const int z = blockIdx.y;
  const int i = (blockIdx.x * 256 + threadIdx.x) * 8;
  if (i >= a.n[z]) return;
  const float4* s = (const float4*)(a.src[z] + i);
  float4 v0 = s[0], v1 = s[1];
  short8 r;
  r[0] = (short)f2bf(v0.x); r[1] = (short)f2bf(v0.y);
  r[2] = (short)f2bf(v0.z); r[3] = (short)f2bf(v0.w);
  r[4] = (short)f2bf(v1.x); r[5] = (short)f2bf(v1.y);
  r[6] = (short)f2bf(v1.z); r[7] = (short)f2bf(v1.w);
  *(short8*)(a.dst[z] + i) = r;
}

// ---------------- bf16 MFMA GEMM v7: A global->reg, B-only LDS, ONE z per block -------------
// R7 post-mortem: NZ=3 fusion needed ~230 VGPRs; compiler capped at 128 and spilled ~100 regs
// to scratch (WRITE_SIZE 122MB on a 24MB-output dispatch, MfmaUtil 11%). The A-in-reg +
// B-only-LDS mechanism was never at fault. v7 = same mechanism, NZ=1 per z-layer (v5's grid):
//   acc 32 + af0/af1 64 + bfr 16 + addr ~= 130 VGPR -> no spill.
//   Per-CU-tile LDS traffic: 24KB (vs v5's ~144KB that bound R6 at 1257 cyc/tile).
// vmcnt ladder (per-wave FIFO, depth 2): tile kt issues loadA(kt+1)[8 global->reg] then
// stgB(kt+2)[2 cp16]; end-of-tile vmcnt(2) retires B(kt+1)+A(kt+1), leaves B(kt+2) in flight.
// WAR: stgB(kt+2) targets slot(kt-1), drained at each wave's lgkmcnt(0) before the kt-1
// barrier. T1 bijective XCD swizzle; T2 swizzle on B (conflicts measured 0).
struct GemmArgs { const u16* A; const u16* W[3]; void* out[3]; const int* tp; int modes; };

__global__ __launch_bounds__(256, 2) void gemm_mfma(GemmArgs g) {
  constexpr int SLOT = 8192;                  // B tile: 64 rows x 64 k x 2B
  __shared__ __align__(16) char lds[3 * SLOT];

  const int tid = threadIdx.x, lane = tid & 63, w = tid >> 6;
  const int wm = w >> 1, wn = w & 1;
  const int t = lane & 15, u = lane >> 4;
  const int l3 = lane >> 3, l7 = lane & 7;
  const int z = blockIdx.z;

  // T1: bijective XCD-chunked remap, nwg = 16x32 = 512 (per z-layer)
  const int flat = (int)blockIdx.x + ((int)blockIdx.y << 4);
  const int swz = (flat & 7) * 64 + (flat >> 3);
  const int m0 = (swz >> 4) * 128;            // 32 m-blocks of 128
  const int n0 = (swz & 15) * 64;             // 16 n-blocks of 64

  const int axor = l7 << 4;                   // B read-side XOR: (row&7)<<4
  const int ksw = (l7 ^ l3) * 8;              // B staging source col pre-swizzle
  const u16* __restrict__ Wb = g.W[z] + (size_t)(n0 + l3) * 1024 + ksw;
  const u16* __restrict__ Arow = g.A + (size_t)(m0 + wm * 64 + t) * 1024 + u * 8;

  auto stgB = [&](char* sb, int kt) {
    #pragma unroll
    for (int r = 0; r < 2; r++)               // row-blocks w*2+r (8 rows x 128B each)
      cp16(Wb + (size_t)(w * 2 + r) * 8192 + kt * 64, sb + (w * 2 + r) * 1024);
  };
  auto loadA = [&](short8 (&af)[2][4], int kt) {
    #pragma unroll
    for (int ks = 0; ks < 2; ks++)
      #pragma unroll
      for (int mf = 0; mf < 4; mf++)
        af[ks][mf] = *(const short8*)(Arow + (size_t)mf * 16384 + kt * 64 + ks * 32);
  };

  const f32x4 fz = {0.f, 0.f, 0.f, 0.f};
  f32x4 acc[4][2];
  #pragma unroll
  for (int i = 0; i < 4; i++) { acc[i][0] = fz; acc[i][1] = fz; }

  short8 af0[2][4], af1[2][4];
  loadA(af0, 0);
  stgB(lds, 0);
  stgB(lds + SLOT, 1);
  asm volatile("s_waitcnt vmcnt(2)" ::: "memory");   // retire A(0)+B(0); B(1) in flight
  __builtin_amdgcn_s_barrier();

  int rs_ = 0, ss_ = 2;
  auto tile = [&](int kt, short8 (&afU)[2][4], short8 (&afL)[2][4]) {
    const char* cs = lds + rs_ * SLOT;
    if (kt + 1 < 16) loadA(afL, kt + 1);
    if (kt + 2 < 16) stgB(lds + ss_ * SLOT, kt + 2);

    short8 bfr[2][2];
    #pragma unroll
    for (int ks = 0; ks < 2; ks++) {
      const int co = (ks * 64 + u * 16) ^ axor;
      const char* bp = cs + (wn * 32 + t) * 128 + co;
      bfr[ks][0] = *(const short8*)(bp);
      bfr[ks][1] = *(const short8*)(bp + 2048);
    }
    asm volatile("s_waitcnt lgkmcnt(0)" ::: "memory");
    __builtin_amdgcn_sched_barrier(0);        // rule #18
    __builtin_amdgcn_s_setprio(1);
    #pragma unroll
    for (int ks = 0; ks < 2; ks++)
      #pragma unroll
      for (int mf = 0; mf < 4; mf++)
        #pragma unroll
        for (int nf = 0; nf < 2; nf++)
          acc[mf][nf] = __builtin_amdgcn_mfma_f32_16x16x32_bf16(afU[ks][mf], bfr[ks][nf], acc[mf][nf], 0, 0, 0);
    __builtin_amdgcn_s_setprio(0);

    if (kt + 2 < 16)      { asm volatile("s_waitcnt vmcnt(2)" ::: "memory"); }
    else if (kt + 1 < 16) { asm volatile("s_waitcnt vmcnt(0)" ::: "memory"); }
    __builtin_amdgcn_s_barrier();
    rs_ = (rs_ == 2) ? 0 : rs_ + 1;
    ss_ = (ss_ == 2) ? 0 : ss_ + 1;
  };
  for (int k2 = 0; k2 < 16; k2 += 2) { tile(k2, af0, af1); tile(k2 + 1, af1, af0); }

  const int mode = (g.modes >> (2 * z)) & 3;
  const int rbase = m0 + wm * 64 + u * 4;
  const int cbase = n0 + wn * 32 + t;
  if (mode == 1) {
    // V^T store
    u16* O = (u16*)g.out[z];
    #pragma unroll
    for (int mt = 0; mt < 4; mt++)
      #pragma unroll
      for (int nt = 0; nt < 2; nt++) {
        int gr = rbase + mt * 16;
        int b = gr >> 11, s0 = gr & (S_ - 1);
        int gc = cbase + nt * 16;
        int h = gc >> 6, d = gc & 63;
        ushort4 v;
        v.x = f2bf(acc[mt][nt][0]); v.y = f2bf(acc[mt][nt][1]);
        v.z = f2bf(acc[mt][nt][2]); v.w = f2bf(acc[mt][nt][3]);
        *(ushort4*)&O[(size_t)((b * 16 + h) * 64 + d) * 2048 + s0] = v;
      }
  } else if (mode == 2) {
    float* O = (float*)g.out[z];
    #pragma unroll
    for (int mt = 0; mt < 4; mt++)
      #pragma unroll
      for (int nt = 0; nt < 2; nt++)
        #pragma unroll
        for (int r = 0; r < 4; r++)
          O[(size_t)(rbase + mt * 16 + r) * 1024 + cbase + nt * 16] = acc[mt][nt][r];
  } else {
    // mode 3: bf16 + fused RoPE (z0 = Q with softmax pre-scale, z1 = K)
    u16* O = (u16*)g.out[z];
    const float osc = (z == 0) ? 0.18033688011112042f : 1.0f;   // 0.125 * log2(e)
    const float sgn = (cbase & 1) ? 1.0f : -1.0f;
    #pragma unroll
    for (int mt = 0; mt < 4; mt++)
      #pragma unroll
      for (int r = 0; r < 4; r++) {
        const int gr = rbase + mt * 16 + r;
        const float pos = (float)g.tp[gr & (S_ - 1)];
        #pragma unroll
        for (int nt = 0; nt < 2; nt++) {
          const int d = (cbase + nt * 16) & 63;
          const float x = acc[mt][nt][r];
          const float p = __shfl_xor(x, 1, 64);               // partner (d^1), lane t^1
          const float inv = exp2f(-(float)(d & ~1) * 0.20762050593046439f);
          float sn, cs;
          sincosf(pos * inv, &sn, &cs);
          O[(size_t)gr * 1024 + cbase + nt * 16] = f2bf((x * cs + p * sgn * sn) * osc);
        }
      }
  }
}

// ---------------- MFMA flash attention v7: v5 + both-sides LDS chunk swizzle ----------------
// (byte-identical to R7's attn, which passed; conflicts 4-way -> 2-way on all frag reads)
__global__ __launch_bounds__(512, 4) void attn_mfma(const u16* __restrict__ qb, const u16* __restrict__ kb,
                                                    const u16* __restrict__ vt, u16* __restrict__ ab) {
  __shared__ __align__(16) u16 Qs[2][4096];
  __shared__ __align__(16) u16 Ks[2][4096];
  __shared__ __align__(16) u16 Vs[2][4096];

  const int tid = threadIdx.x, lane = tid & 63, w = tid >> 6;
  const int v = w & 3, g = w >> 2;
  const int t = lane & 15, u = lane >> 4;
  const int bh = blockIdx.y, b = bh >> 4, h = bh & 15;
  const int i = blockIdx.x;              // 0..15
  const int qa = 31 - i;                 // tile A (long)
  const int qbt = i;                     // tile B (short)
  const int nk = 32 - i;                 // K/V stream length in 64-key tiles
  const size_t qkb = (size_t)b * S_ * 1024 + h * 64;
  const size_t vtb = (size_t)bh * 64 * 2048;
  const int ux2 = u << 1;                // read-side row XOR

  {
    const int qtile = g ? qbt : qa;
    const int lsw = lane ^ (v << 1);     // staged row permute for chunks v, v+4
    cp16(qb + qkb + (size_t)(qtile * 64 + lsw) * 1024 + v * 8,       (char*)Qs[g] + v * 1024);
    cp16(qb + qkb + (size_t)(qtile * 64 + lsw) * 1024 + (v + 4) * 8, (char*)Qs[g] + 4096 + v * 1024);
  }
  {
    const int lsw = lane ^ ((w & 3) << 1);
    cp16(kb + qkb + (size_t)lsw * 1024 + w * 8, (char*)Ks[0] + w * 1024);
    cp16(vt + vtb + (size_t)lsw * 2048 + w * 8, (char*)Vs[0] + w * 1024);
  }
  __syncthreads();

  short8 aqA[2], aqP[2];
  #pragma unroll
  for (int ks = 0; ks < 2; ks++) {
    const int ro = ((v * 16 + t) ^ ux2) * 16;
    aqA[ks] = *(const short8*)((const char*)Qs[0] + (ks * 4 + u) * 1024 + ro);
    short8 bq = *(const short8*)((const char*)Qs[1] + (ks * 4 + u) * 1024 + ro);
    aqP[ks] = g ? bq : aqA[ks];
  }

  const f32x4 fzero = {0.f, 0.f, 0.f, 0.f};
  f32x4 oPrim[4], oSec[4];
  #pragma unroll
  for (int ct = 0; ct < 4; ct++) { oPrim[ct] = fzero; oSec[ct] = fzero; }
  float rsumP = 0.f, rsumS = 0.f;

  const int qprim = g ? qbt : qa;
  const int qrowP = qprim * 64 + v * 16 + t;
  const int qrowA = qa * 64 + v * 16 + t;

  for (int kt = 0; kt < nk; kt++) {
    const int cur = kt & 1, nxt = cur ^ 1;
    if (kt + 1 < nk) {
      const int lsw = lane ^ ((w & 3) << 1);
      cp16(kb + qkb + (size_t)((kt + 1) * 64 + lsw) * 1024 + w * 8, (char*)Ks[nxt] + w * 1024);
      cp16(vt + vtb + (size_t)lsw * 2048 + (kt + 1) * 64 + w * 8,   (char*)Vs[nxt] + w * 1024);
    }

    if (kt <= qbt) {
      // ---- FULL PHASE ----
      f32x4 st[4] = {fzero, fzero, fzero, fzero};
      __builtin_amdgcn_s_setprio(1);
      #pragma unroll
      for (int ks = 0; ks < 2; ks++)
        #pragma unroll
        for (int ct = 0; ct < 4; ct++) {
          short8 kf = *(const short8*)((const char*)Ks[cur] + (ks * 4 + u) * 1024 + ((ct * 16 + t) ^ ux2) * 16);
          st[ct] = __builtin_amdgcn_mfma_f32_16x16x32_bf16(kf, aqP[ks], st[ct], 0, 0, 0);
        }
      __builtin_amdgcn_s_setprio(0);

      unsigned pb2[4][2];
      if (kt == qprim) {
        #pragma unroll
        for (int ct = 0; ct < 4; ct++) {
          float p[4];
          #pragma unroll
          for (int r = 0; r < 4; r++) {
            int key = kt * 64 + ct * 16 + 4 * u + r;
            float pv = exp2f(st[ct][r]);
            p[r] = (key > qrowP) ? 0.f : pv;
          }
          rsumP += (p[0] + p[1]) + (p[2] + p[3]);
          pb2[ct][0] = pack_bf2(p[0], p[1]);
          pb2[ct][1] = pack_bf2(p[2], p[3]);
        }
      } else {
        #pragma unroll
        for (int ct = 0; ct < 4; ct++) {
          float p[4];
          #pragma unroll
          for (int r = 0; r < 4; r++) p[r] = exp2f(st[ct][r]);
          rsumP += (p[0] + p[1]) + (p[2] + p[3]);
          pb2[ct][0] = pack_bf2(p[0], p[1]);
          pb2[ct][1] = pack_bf2(p[2], p[3]);
        }
      }

      #pragma unroll
      for (int ks = 0; ks < 2; ks++) {
        union { short8 s8; int i4[4]; } pf;
        #pragma unroll
        for (int jj = 0; jj < 4; jj++) {
          int src = 32 * (u & 1) + 16 * (jj >> 1) + t;
          int v0 = __shfl((int)pb2[ks * 2][jj & 1], src, 64);
          int v1 = __shfl((int)pb2[ks * 2 + 1][jj & 1], src, 64);
          pf.i4[jj] = (u >> 1) ? v1 : v0;
        }
        __builtin_amdgcn_s_setprio(1);
        #pragma unroll
        for (int ct = 0; ct < 4; ct++) {
          short8 vf = *(const short8*)((const char*)Vs[cur] + (ks * 4 + u) * 1024 + ((ct * 16 + t) ^ ux2) * 16);
          oPrim[ct] = __builtin_amdgcn_mfma_f32_16x16x32_bf16(vf, pf.s8, oPrim[ct], 0, 0, 0);
        }
        __builtin_amdgcn_s_setprio(0);
      }
    } else {
      // ---- HALF PHASE ----
      f32x4 st2[2] = {fzero, fzero};
      __builtin_amdgcn_s_setprio(1);
      #pragma unroll
      for (int ks = 0; ks < 2; ks++)
        #pragma unroll
        for (int c = 0; c < 2; c++) {
          short8 kf = *(const short8*)((const char*)Ks[cur] + (ks * 4 + u) * 1024 + (((2 * g + c) * 16 + t) ^ ux2) * 16);
          st2[c] = __builtin_amdgcn_mfma_f32_16x16x32_bf16(kf, aqA[ks], st2[c], 0, 0, 0);
        }
      __builtin_amdgcn_s_setprio(0);

      unsigned ph[2][2];
      float rs = 0.f;
      if (kt == qa) {
        #pragma unroll
        for (int c = 0; c < 2; c++) {
          float p[4];
          #pragma unroll
          for (int r = 0; r < 4; r++) {
            int key = kt * 64 + (2 * g + c) * 16 + 4 * u + r;
            float pv = exp2f(st2[c][r]);
            p[r] = (key > qrowA) ? 0.f : pv;
          }
          rs += (p[0] + p[1]) + (p[2] + p[3]);
          ph[c][0] = pack_bf2(p[0], p[1]);
          ph[c][1] = pack_bf2(p[2], p[3]);
        }
      } else {
        #pragma unroll
        for (int c = 0; c < 2; c++) {
          float p[4];
          #pragma unroll
          for (int r = 0; r < 4; r++) p[r] = exp2f(st2[c][r]);
          rs += (p[0] + p[1]) + (p[2] + p[3]);
          ph[c][0] = pack_bf2(p[0], p[1]);
          ph[c][1] = pack_bf2(p[2], p[3]);
        }
      }

      union { short8 s8; int i4[4]; } pf;
      #pragma unroll
      for (int jj = 0; jj < 4; jj++) {
        int src = 32 * (u & 1) + 16 * (jj >> 1) + t;
        int v0 = __shfl((int)ph[0][jj & 1], src, 64);
        int v1 = __shfl((int)ph[1][jj & 1], src, 64);
        pf.i4[jj] = (u >> 1) ? v1 : v0;
      }
      if (g) {
        rsumS += rs;
        __builtin_amdgcn_s_setprio(1);
        #pragma unroll
        for (int ct = 0; ct < 4; ct++) {
          short8 vf = *(const short8*)((const char*)Vs[cur] + (4 + u) * 1024 + ((ct * 16 + t) ^ ux2) * 16);
          oSec[ct] = __builtin_amdgcn_mfma_f32_16x16x32_bf16(vf, pf.s8, oSec[ct], 0, 0, 0);
        }
        __builtin_amdgcn_s_setprio(0);
      } else {
        rsumP += rs;
        __builtin_amdgcn_s_setprio(1);
        #pragma unroll
        for (int ct = 0; ct < 4; ct++) {
          short8 vf = *(const short8*)((const char*)Vs[cur] + u * 1024 + ((ct * 16 + t) ^ ux2) * 16);
          oPrim[ct] = __builtin_amdgcn_mfma_f32_16x16x32_bf16(vf, pf.s8, oPrim[ct], 0, 0, 0);
        }
        __builtin_amdgcn_s_setprio(0);
      }
    }
    __syncthreads();
  }

  // ---- epilogue ----
  float* dmpO = (float*)Ks;
  float* dmpR = (float*)Vs;
  if (g) {
    #pragma unroll
    for (int ct = 0; ct < 4; ct++)
      *(f32x4*)&dmpO[(size_t)(v * 64 + lane) * 16 + ct * 4] = oSec[ct];
    dmpR[v * 64 + lane] = rsumS;
    float rs = rsumP;
    rs += __shfl_xor(rs, 16, 64);
    rs += __shfl_xor(rs, 32, 64);
    const float inv = 1.0f / rs;
    #pragma unroll
    for (int ct = 0; ct < 4; ct++) {
      ushort4 vv;
      vv.x = f2bf(oPrim[ct][0] * inv); vv.y = f2bf(oPrim[ct][1] * inv);
      vv.z = f2bf(oPrim[ct][2] * inv); vv.w = f2bf(oPrim[ct][3] * inv);
      *(ushort4*)&ab[((size_t)b * S_ + qrowP) * 1024 + h * 64 + ct * 16 + 4 * u] = vv;
    }
  }
  __syncthreads();
  if (!g) {
    #pragma unroll
    for (int ct = 0; ct < 4; ct++) {
      f32x4 add = *(const f32x4*)&dmpO[(size_t)(v * 64 + lane) * 16 + ct * 4];
      oPrim[ct] += add;
    }
    float rs = rsumP + dmpR[v * 64 + lane];
    rs += __shfl_xor(rs, 16, 64);
    rs += __shfl_xor(rs, 32, 64);
    const float inv = 1.0f / rs;
    #pragma unroll
    for (int ct = 0; ct < 4; ct++) {
      ushort4 vv;
      vv.x = f2bf(oPrim[ct][0] * inv); vv.y = f2bf(oPrim[ct][1] * inv);
      vv.z = f2bf(oPrim[ct][2] * inv); vv.w = f2bf(oPrim[ct][3] * inv);
      *(ushort4*)&ab[((size_t)b * S_ + qrowA) * 1024 + h * 64 + ct * 16 + 4 * u] = vv;
    }
  }
}

extern "C" void kernel_launch(void* const* d_in, const int* in_sizes, int n_in,
                              void* d_out, int out_size, void* d_ws, size_t ws_size,
                              hipStream_t stream) {
  const float* x  = (const float*)d_in[0];
  const float* Wq = (const float*)d_in[1];
  const float* Wk = (const float*)d_in[2];
  const float* Wv = (const float*)d_in[3];
  const float* Wo = (const float*)d_in[4];
  const int*   tp = (const int*)d_in[5];
  float* out = (float*)d_out;

  char* ws = (char*)d_ws;
  u16* xb  = (u16*)(ws);                       // 8 MB
  u16* wqb = (u16*)(ws + (8 << 20));           // 2 MB each
  u16* wkb = (u16*)(ws + (10 << 20));
  u16* wvb = (u16*)(ws + (12 << 20));
  u16* wob = (u16*)(ws + (14 << 20));
  u16* qbuf = (u16*)(ws + (16 << 20));         // 8 MB
  u16* kbuf = (u16*)(ws + (24 << 20));
  u16* vtb  = (u16*)(ws + (32 << 20));
  u16* abuf = (u16*)(ws + (40 << 20));

  CastArgs ca;
  ca.src[0] = x;  ca.dst[0] = xb;  ca.n[0] = 2 * S_ * DM_;
  ca.src[1] = Wq; ca.dst[1] = wqb; ca.n[1] = DM_ * DM_;
  ca.src[2] = Wk; ca.dst[2] = wkb; ca.n[2] = DM_ * DM_;
  ca.src[3] = Wv; ca.dst[3] = wvb; ca.n[3] = DM_ * DM_;
  ca.src[4] = Wo; ca.dst[4] = wob; ca.n[4] = DM_ * DM_;
  cast_kernel<<<dim3(2048, 5), 256, 0, stream>>>(ca);

  GemmArgs gq;
  gq.A = xb;
  gq.W[0] = wqb; gq.W[1] = wkb; gq.W[2] = wvb;
  gq.out[0] = qbuf; gq.out[1] = kbuf; gq.out[2] = vtb;
  gq.tp = tp;
  gq.modes = 3 | (3 << 2) | (1 << 4);          // z0: Q rope+scale; z1: K rope; z2: Vt
  gemm_mfma<<<dim3(16, 32, 3), 256, 0, stream>>>(gq);

  attn_mfma<<<dim3(16, 32), 512, 0, stream>>>(qbuf, kbuf, vtb, abuf);

  GemmArgs go;
  go.A = abuf;
  go.W[0] = wob; go.W[1] = wob; go.W[2] = wob;
  go.out[0] = out; go.out[1] = out; go.out[2] = out;
  go.tp = tp;
  go.modes = 2;                                // fp32 out
  gemm_mfma<<<dim3(16, 32, 1), 256, 0, stream>>>(go);
}

// Round 9
// 182.822 us; speedup vs baseline: 1.4372x; 1.4372x over previous
//
#include <hip/hip_runtime.h>
#include <hip/hip_bf16.h>
#include <math.h>

#define S_  2048
#define DM_ 1024

typedef unsigned short u16;
typedef __attribute__((ext_vector_type(8))) short short8;
typedef __attribute__((ext_vector_type(4))) float f32x4;

__device__ __forceinline__ u16 f2bf(float f) {
  unsigned u = __float_as_uint(f);
  u += 0x7fffu + ((u >> 16) & 1u);           // RNE
  return (u16)(u >> 16);
}
__device__ __forceinline__ float bf2f(u16 h) {
  return __uint_as_float((unsigned)h << 16);
}
__device__ __forceinline__ unsigned pack_bf2(float a, float b) {
  union { __hip_bfloat162 h2; unsigned u; } cv;
  cv.h2 = __float22bfloat162_rn(float2{a, b});   // v_cvt_pk_bf16_f32 on gfx950
  return cv.u;
}
// async global->LDS, 16B per lane. LDS dest is wave-uniform base + lane*16.
__device__ __forceinline__ void cp16(const void* g, void* l) {
  __builtin_amdgcn_global_load_lds(
      (const __attribute__((address_space(1))) unsigned*)(uintptr_t)g,
      (__attribute__((address_space(3))) unsigned*)(unsigned)(uintptr_t)l, 16, 0, 0);
}

// ---------------- fp32 -> bf16 cast ----------------
struct CastArgs { const float* src[5]; u16* dst[5]; int n[5]; };

__global__ __launch_bounds__(256) void cast_kernel(CastArgs a) {
  const int z = blockIdx.y;
  const int i = (blockIdx.x * 256 + threadIdx.x) * 8;
  if (i >= a.n[z]) return;
  const float4* s = (const float4*)(a.src[z] + i);
  float4 v0 = s[0], v1 = s[1];
  short8 r;
  r[0] = (short)f2bf(v0.x); r[1] = (short)f2bf(v0.y);
  r[2] = (short)f2bf(v0.z); r[3] = (short)f2bf(v0.w);
  r[4] = (short)f2bf(v1.x); r[5] = (short)f2bf(v1.y);
  r[6] = (short)f2bf(v1.z); r[7] = (short)f2bf(v1.w);
  *(short8*)(a.dst[z] + i) = r;
}

// ---------------- bf16 MFMA GEMM v4 (R4-proven best: 183.9us total) ----------------
// 128x64 tile, A+B in LDS, 3-slot depth-2 counted-vmcnt. R7/R8 falsified the A-in-reg
// variants (spill at NZ=3; uncoalesced 16-segment A loads + 1-tile-deep latency at NZ=1).
// This version is restored byte-identical to R4. Per tile: stage(kt+2) | read 12 frags |
// lgkmcnt(0)+sched_barrier | setprio 16 MFMA | vmcnt(6) | s_barrier.
struct GemmArgs { const u16* A; const u16* W[3]; void* out[3]; int modes; };

template<int GXL>
__global__ __launch_bounds__(256, 2) void gemm_mfma(GemmArgs g) {
  constexpr int BM = 128, BN = 64;
  constexpr int ABYTES = BM * 64 * 2;         // 16 KB
  constexpr int SLOT = ABYTES + BN * 64 * 2;  // 24 KB
  __shared__ __align__(16) char lds[3 * SLOT];

  const int tid = threadIdx.x, lane = tid & 63, w = tid >> 6;
  const int wm = w >> 1, wn = w & 1;
  const int t = lane & 15, u = lane >> 4;
  const int l3 = lane >> 3, l7 = lane & 7;
  const int z = blockIdx.z;

  // T1: bijective XCD-chunked remap (nwg = 512)
  const int nwg = (int)gridDim.y << GXL;
  const int flat = (int)blockIdx.x + ((int)blockIdx.y << GXL);
  const int swz = (flat & 7) * (nwg >> 3) + (flat >> 3);
  const int m0 = (swz >> GXL) * BM;
  const int n0 = (swz & ((1 << GXL) - 1)) * BN;

  const u16* __restrict__ A = g.A;
  const u16* __restrict__ W = g.W[z];

  const int axor = l7 << 4;                   // read-side XOR: (row&7)<<4
  const int ksw = (l7 ^ l3) * 8;              // staging source col pre-swizzle
  const u16* Ab = A + (size_t)(m0 + l3) * 1024 + ksw;
  const u16* Wb = W + (size_t)(n0 + l3) * 1024 + ksw;

  auto stg = [&](char* sb, int kt) {
    #pragma unroll
    for (int r = 0; r < 4; r++)               // A: 4 row-blocks/wave (8 rows x 128B each)
      cp16(Ab + (size_t)(w * 4 + r) * 8192 + kt * 64, sb + (w * 4 + r) * 1024);
    #pragma unroll
    for (int r = 0; r < 2; r++)               // B: 2 row-blocks/wave
      cp16(Wb + (size_t)(w * 2 + r) * 8192 + kt * 64, sb + ABYTES + (w * 2 + r) * 1024);
  };

  const f32x4 fz = {0.f, 0.f, 0.f, 0.f};
  f32x4 acc[4][2];
  #pragma unroll
  for (int i = 0; i < 4; i++) { acc[i][0] = fz; acc[i][1] = fz; }

  // prologue: land kt0; kt1's 6 loads stay in flight
  stg(lds, 0);
  stg(lds + SLOT, 1);
  asm volatile("s_waitcnt vmcnt(6)" ::: "memory");
  __builtin_amdgcn_s_barrier();

  int rs_ = 0, ss_ = 2;                       // slot of kt, slot of kt+2
  for (int kt = 0; kt < 16; kt++) {
    const char* cs = lds + rs_ * SLOT;
    if (kt + 2 < 16) stg(lds + ss_ * SLOT, kt + 2);

    short8 af[2][4], bfr[2][2];
    #pragma unroll
    for (int ks = 0; ks < 2; ks++) {
      const int co = (ks * 64 + u * 16) ^ axor;
      const char* ap = cs + (wm * 64 + t) * 128 + co;
      const char* bp = cs + ABYTES + (wn * 32 + t) * 128 + co;
      #pragma unroll
      for (int mf = 0; mf < 4; mf++) af[ks][mf] = *(const short8*)(ap + mf * 2048);
      #pragma unroll
      for (int nf = 0; nf < 2; nf++) bfr[ks][nf] = *(const short8*)(bp + nf * 2048);
    }
    asm volatile("s_waitcnt lgkmcnt(0)" ::: "memory");
    __builtin_amdgcn_sched_barrier(0);        // rule #18
    __builtin_amdgcn_s_setprio(1);
    #pragma unroll
    for (int ks = 0; ks < 2; ks++)
      #pragma unroll
      for (int mf = 0; mf < 4; mf++)
        #pragma unroll
        for (int nf = 0; nf < 2; nf++)
          acc[mf][nf] = __builtin_amdgcn_mfma_f32_16x16x32_bf16(af[ks][mf], bfr[ks][nf], acc[mf][nf], 0, 0, 0);
    __builtin_amdgcn_s_setprio(0);

    if (kt + 2 < 16)      { asm volatile("s_waitcnt vmcnt(6)" ::: "memory"); }
    else if (kt + 1 < 16) { asm volatile("s_waitcnt vmcnt(0)" ::: "memory"); }
    __builtin_amdgcn_s_barrier();
    rs_ = (rs_ == 2) ? 0 : rs_ + 1;
    ss_ = (ss_ == 2) ? 0 : ss_ + 1;
  }

  const int mode = (g.modes >> (2 * z)) & 3;
  const int rbase = m0 + wm * 64 + u * 4;
  const int cbase = n0 + wn * 32 + t;
  if (mode == 0) {
    u16* O = (u16*)g.out[z];
    #pragma unroll
    for (int mt = 0; mt < 4; mt++)
      #pragma unroll
      for (int nt = 0; nt < 2; nt++)
        #pragma unroll
        for (int r = 0; r < 4; r++)
          O[(size_t)(rbase + mt * 16 + r) * 1024 + cbase + nt * 16] = f2bf(acc[mt][nt][r]);
  } else if (mode == 1) {
    u16* O = (u16*)g.out[z];
    #pragma unroll
    for (int mt = 0; mt < 4; mt++)
      #pragma unroll
      for (int nt = 0; nt < 2; nt++) {
        int gr = rbase + mt * 16;
        int b = gr >> 11, s0 = gr & (S_ - 1);
        int gc = cbase + nt * 16;
        int h = gc >> 6, d = gc & 63;
        ushort4 v;
        v.x = f2bf(acc[mt][nt][0]); v.y = f2bf(acc[mt][nt][1]);
        v.z = f2bf(acc[mt][nt][2]); v.w = f2bf(acc[mt][nt][3]);
        *(ushort4*)&O[(size_t)((b * 16 + h) * 64 + d) * 2048 + s0] = v;
      }
  } else {
    float* O = (float*)g.out[z];
    #pragma unroll
    for (int mt = 0; mt < 4; mt++)
      #pragma unroll
      for (int nt = 0; nt < 2; nt++)
        #pragma unroll
        for (int r = 0; r < 4; r++)
          O[(size_t)(rbase + mt * 16 + r) * 1024 + cbase + nt * 16] = acc[mt][nt][r];
  }
}

// ---------------- RoPE in-place on bf16 q/k; q PRE-SCALED by 0.125*log2(e) ----------------
// Kept as a separate kernel: R6 measured the fused-epilogue variant net -2.7us WORSE
// (epilogue sincos cost exceeded the saved kernel + round-trip).
__global__ __launch_bounds__(256) void rope_kernel(u16* qb, u16* kb, const int* __restrict__ tp) {
  const int isq = (blockIdx.y == 0);
  u16* p = isq ? qb : kb;
  const float outscale = isq ? 0.18033688011112042f : 1.0f;   // 0.125 * log2(e)
  const int i = (blockIdx.x * 256 + threadIdx.x) * 8;
  const int s = (i >> 10) & (S_ - 1);
  const int d = i & 63;
  const float pos = (float)tp[s];
  short8 v = *(short8*)(p + i);
  #pragma unroll
  for (int j = 0; j < 4; j++) {
    float inv = exp2f(-(float)(d + 2 * j) * 0.20762050593046439f);  // log2(10000)/64
    float phi = pos * inv;
    float sn, cs;
    sincosf(phi, &sn, &cs);
    float xe = bf2f((u16)v[2 * j]), xo = bf2f((u16)v[2 * j + 1]);
    v[2 * j]     = (short)f2bf((xe * cs - xo * sn) * outscale);
    v[2 * j + 1] = (short)f2bf((xe * sn + xo * cs) * outscale);
  }
  *(short8*)(p + i) = v;
}

// ---------------- MFMA flash attention v7: R4's v5 + both-sides LDS chunk swizzle ------------
// Single delta vs R4's attn: the 4-way bank conflict on K/V/Q frag reads (R6 counter: 2.46M
// conflict-cycles/dispatch) fixed by staging chunk w with source row lane^((w&3)<<1) and
// reading row ^ (u<<1) -- same involution both sides. Passed correctness in R7 and R8.
__global__ __launch_bounds__(512, 4) void attn_mfma(const u16* __restrict__ qb, const u16* __restrict__ kb,
                                                    const u16* __restrict__ vt, u16* __restrict__ ab) {
  __shared__ __align__(16) u16 Qs[2][4096];
  __shared__ __align__(16) u16 Ks[2][4096];
  __shared__ __align__(16) u16 Vs[2][4096];

  const int tid = threadIdx.x, lane = tid & 63, w = tid >> 6;
  const int v = w & 3, g = w >> 2;
  const int t = lane & 15, u = lane >> 4;
  const int bh = blockIdx.y, b = bh >> 4, h = bh & 15;
  const int i = blockIdx.x;              // 0..15
  const int qa = 31 - i;                 // tile A (long)
  const int qbt = i;                     // tile B (short)
  const int nk = 32 - i;                 // K/V stream length in 64-key tiles
  const size_t qkb = (size_t)b * S_ * 1024 + h * 64;
  const size_t vtb = (size_t)bh * 64 * 2048;
  const int ux2 = u << 1;                // read-side row XOR

  {
    const int qtile = g ? qbt : qa;
    const int lsw = lane ^ (v << 1);     // staged row permute for chunks v, v+4
    cp16(qb + qkb + (size_t)(qtile * 64 + lsw) * 1024 + v * 8,       (char*)Qs[g] + v * 1024);
    cp16(qb + qkb + (size_t)(qtile * 64 + lsw) * 1024 + (v + 4) * 8, (char*)Qs[g] + 4096 + v * 1024);
  }
  {
    const int lsw = lane ^ ((w & 3) << 1);
    cp16(kb + qkb + (size_t)lsw * 1024 + w * 8, (char*)Ks[0] + w * 1024);
    cp16(vt + vtb + (size_t)lsw * 2048 + w * 8, (char*)Vs[0] + w * 1024);
  }
  __syncthreads();

  short8 aqA[2], aqP[2];
  #pragma unroll
  for (int ks = 0; ks < 2; ks++) {
    const int ro = ((v * 16 + t) ^ ux2) * 16;
    aqA[ks] = *(const short8*)((const char*)Qs[0] + (ks * 4 + u) * 1024 + ro);
    short8 bq = *(const short8*)((const char*)Qs[1] + (ks * 4 + u) * 1024 + ro);
    aqP[ks] = g ? bq : aqA[ks];
  }

  const f32x4 fzero = {0.f, 0.f, 0.f, 0.f};
  f32x4 oPrim[4], oSec[4];
  #pragma unroll
  for (int ct = 0; ct < 4; ct++) { oPrim[ct] = fzero; oSec[ct] = fzero; }
  float rsumP = 0.f, rsumS = 0.f;

  const int qprim = g ? qbt : qa;
  const int qrowP = qprim * 64 + v * 16 + t;
  const int qrowA = qa * 64 + v * 16 + t;

  for (int kt = 0; kt < nk; kt++) {
    const int cur = kt & 1, nxt = cur ^ 1;
    if (kt + 1 < nk) {
      const int lsw = lane ^ ((w & 3) << 1);
      cp16(kb + qkb + (size_t)((kt + 1) * 64 + lsw) * 1024 + w * 8, (char*)Ks[nxt] + w * 1024);
      cp16(vt + vtb + (size_t)lsw * 2048 + (kt + 1) * 64 + w * 8,   (char*)Vs[nxt] + w * 1024);
    }

    if (kt <= qbt) {
      // ---- FULL PHASE ----
      f32x4 st[4] = {fzero, fzero, fzero, fzero};
      __builtin_amdgcn_s_setprio(1);
      #pragma unroll
      for (int ks = 0; ks < 2; ks++)
        #pragma unroll
        for (int ct = 0; ct < 4; ct++) {
          short8 kf = *(const short8*)((const char*)Ks[cur] + (ks * 4 + u) * 1024 + ((ct * 16 + t) ^ ux2) * 16);
          st[ct] = __builtin_amdgcn_mfma_f32_16x16x32_bf16(kf, aqP[ks], st[ct], 0, 0, 0);
        }
      __builtin_amdgcn_s_setprio(0);

      unsigned pb2[4][2];
      if (kt == qprim) {
        #pragma unroll
        for (int ct = 0; ct < 4; ct++) {
          float p[4];
          #pragma unroll
          for (int r = 0; r < 4; r++) {
            int key = kt * 64 + ct * 16 + 4 * u + r;
            float pv = exp2f(st[ct][r]);
            p[r] = (key > qrowP) ? 0.f : pv;
          }
          rsumP += (p[0] + p[1]) + (p[2] + p[3]);
          pb2[ct][0] = pack_bf2(p[0], p[1]);
          pb2[ct][1] = pack_bf2(p[2], p[3]);
        }
      } else {
        #pragma unroll
        for (int ct = 0; ct < 4; ct++) {
          float p[4];
          #pragma unroll
          for (int r = 0; r < 4; r++) p[r] = exp2f(st[ct][r]);
          rsumP += (p[0] + p[1]) + (p[2] + p[3]);
          pb2[ct][0] = pack_bf2(p[0], p[1]);
          pb2[ct][1] = pack_bf2(p[2], p[3]);
        }
      }

      #pragma unroll
      for (int ks = 0; ks < 2; ks++) {
        union { short8 s8; int i4[4]; } pf;
        #pragma unroll
        for (int jj = 0; jj < 4; jj++) {
          int src = 32 * (u & 1) + 16 * (jj >> 1) + t;
          int v0 = __shfl((int)pb2[ks * 2][jj & 1], src, 64);
          int v1 = __shfl((int)pb2[ks * 2 + 1][jj & 1], src, 64);
          pf.i4[jj] = (u >> 1) ? v1 : v0;
        }
        __builtin_amdgcn_s_setprio(1);
        #pragma unroll
        for (int ct = 0; ct < 4; ct++) {
          short8 vf = *(const short8*)((const char*)Vs[cur] + (ks * 4 + u) * 1024 + ((ct * 16 + t) ^ ux2) * 16);
          oPrim[ct] = __builtin_amdgcn_mfma_f32_16x16x32_bf16(vf, pf.s8, oPrim[ct], 0, 0, 0);
        }
        __builtin_amdgcn_s_setprio(0);
      }
    } else {
      // ---- HALF PHASE ----
      f32x4 st2[2] = {fzero, fzero};
      __builtin_amdgcn_s_setprio(1);
      #pragma unroll
      for (int ks = 0; ks < 2; ks++)
        #pragma unroll
        for (int c = 0; c < 2; c++) {
          short8 kf = *(const short8*)((const char*)Ks[cur] + (ks * 4 + u) * 1024 + (((2 * g + c) * 16 + t) ^ ux2) * 16);
          st2[c] = __builtin_amdgcn_mfma_f32_16x16x32_bf16(kf, aqA[ks], st2[c], 0, 0, 0);
        }
      __builtin_amdgcn_s_setprio(0);

      unsigned ph[2][2];
      float rs = 0.f;
      if (kt == qa) {
        #pragma unroll
        for (int c = 0; c < 2; c++) {
          float p[4];
          #pragma unroll
          for (int r = 0; r < 4; r++) {
            int key = kt * 64 + (2 * g + c) * 16 + 4 * u + r;
            float pv = exp2f(st2[c][r]);
            p[r] = (key > qrowA) ? 0.f : pv;
          }
          rs += (p[0] + p[1]) + (p[2] + p[3]);
          ph[c][0] = pack_bf2(p[0], p[1]);
          ph[c][1] = pack_bf2(p[2], p[3]);
        }
      } else {
        #pragma unroll
        for (int c = 0; c < 2; c++) {
          float p[4];
          #pragma unroll
          for (int r = 0; r < 4; r++) p[r] = exp2f(st2[c][r]);
          rs += (p[0] + p[1]) + (p[2] + p[3]);
          ph[c][0] = pack_bf2(p[0], p[1]);
          ph[c][1] = pack_bf2(p[2], p[3]);
        }
      }

      union { short8 s8; int i4[4]; } pf;
      #pragma unroll
      for (int jj = 0; jj < 4; jj++) {
        int src = 32 * (u & 1) + 16 * (jj >> 1) + t;
        int v0 = __shfl((int)ph[0][jj & 1], src, 64);
        int v1 = __shfl((int)ph[1][jj & 1], src, 64);
        pf.i4[jj] = (u >> 1) ? v1 : v0;
      }
      if (g) {
        rsumS += rs;
        __builtin_amdgcn_s_setprio(1);
        #pragma unroll
        for (int ct = 0; ct < 4; ct++) {
          short8 vf = *(const short8*)((const char*)Vs[cur] + (4 + u) * 1024 + ((ct * 16 + t) ^ ux2) * 16);
          oSec[ct] = __builtin_amdgcn_mfma_f32_16x16x32_bf16(vf, pf.s8, oSec[ct], 0, 0, 0);
        }
        __builtin_amdgcn_s_setprio(0);
      } else {
        rsumP += rs;
        __builtin_amdgcn_s_setprio(1);
        #pragma unroll
        for (int ct = 0; ct < 4; ct++) {
          short8 vf = *(const short8*)((const char*)Vs[cur] + u * 1024 + ((ct * 16 + t) ^ ux2) * 16);
          oPrim[ct] = __builtin_amdgcn_mfma_f32_16x16x32_bf16(vf, pf.s8, oPrim[ct], 0, 0, 0);
        }
        __builtin_amdgcn_s_setprio(0);
      }
    }
    __syncthreads();
  }

  // ---- epilogue ----
  float* dmpO = (float*)Ks;
  float* dmpR = (float*)Vs;
  if (g) {
    #pragma unroll
    for (int ct = 0; ct < 4; ct++)
      *(f32x4*)&dmpO[(size_t)(v * 64 + lane) * 16 + ct * 4] = oSec[ct];
    dmpR[v * 64 + lane] = rsumS;
    float rs = rsumP;
    rs += __shfl_xor(rs, 16, 64);
    rs += __shfl_xor(rs, 32, 64);
    const float inv = 1.0f / rs;
    #pragma unroll
    for (int ct = 0; ct < 4; ct++) {
      ushort4 vv;
      vv.x = f2bf(oPrim[ct][0] * inv); vv.y = f2bf(oPrim[ct][1] * inv);
      vv.z = f2bf(oPrim[ct][2] * inv); vv.w = f2bf(oPrim[ct][3] * inv);
      *(ushort4*)&ab[((size_t)b * S_ + qrowP) * 1024 + h * 64 + ct * 16 + 4 * u] = vv;
    }
  }
  __syncthreads();
  if (!g) {
    #pragma unroll
    for (int ct = 0; ct < 4; ct++) {
      f32x4 add = *(const f32x4*)&dmpO[(size_t)(v * 64 + lane) * 16 + ct * 4];
      oPrim[ct] += add;
    }
    float rs = rsumP + dmpR[v * 64 + lane];
    rs += __shfl_xor(rs, 16, 64);
    rs += __shfl_xor(rs, 32, 64);
    const float inv = 1.0f / rs;
    #pragma unroll
    for (int ct = 0; ct < 4; ct++) {
      ushort4 vv;
      vv.x = f2bf(oPrim[ct][0] * inv); vv.y = f2bf(oPrim[ct][1] * inv);
      vv.z = f2bf(oPrim[ct][2] * inv); vv.w = f2bf(oPrim[ct][3] * inv);
      *(ushort4*)&ab[((size_t)b * S_ + qrowA) * 1024 + h * 64 + ct * 16 + 4 * u] = vv;
    }
  }
}

extern "C" void kernel_launch(void* const* d_in, const int* in_sizes, int n_in,
                              void* d_out, int out_size, void* d_ws, size_t ws_size,
                              hipStream_t stream) {
  const float* x  = (const float*)d_in[0];
  const float* Wq = (const float*)d_in[1];
  const float* Wk = (const float*)d_in[2];
  const float* Wv = (const float*)d_in[3];
  const float* Wo = (const float*)d_in[4];
  const int*   tp = (const int*)d_in[5];
  float* out = (float*)d_out;

  char* ws = (char*)d_ws;
  u16* xb  = (u16*)(ws);                       // 8 MB
  u16* wqb = (u16*)(ws + (8 << 20));           // 2 MB each
  u16* wkb = (u16*)(ws + (10 << 20));
  u16* wvb = (u16*)(ws + (12 << 20));
  u16* wob = (u16*)(ws + (14 << 20));
  u16* qbuf = (u16*)(ws + (16 << 20));         // 8 MB
  u16* kbuf = (u16*)(ws + (24 << 20));
  u16* vtb  = (u16*)(ws + (32 << 20));
  u16* abuf = (u16*)(ws + (40 << 20));

  CastArgs ca;
  ca.src[0] = x;  ca.dst[0] = xb;  ca.n[0] = 2 * S_ * DM_;
  ca.src[1] = Wq; ca.dst[1] = wqb; ca.n[1] = DM_ * DM_;
  ca.src[2] = Wk; ca.dst[2] = wkb; ca.n[2] = DM_ * DM_;
  ca.src[3] = Wv; ca.dst[3] = wvb; ca.n[3] = DM_ * DM_;
  ca.src[4] = Wo; ca.dst[4] = wob; ca.n[4] = DM_ * DM_;
  cast_kernel<<<dim3(2048, 5), 256, 0, stream>>>(ca);

  GemmArgs gq;
  gq.A = xb;
  gq.W[0] = wqb; gq.W[1] = wkb; gq.W[2] = wvb;
  gq.out[0] = qbuf; gq.out[1] = kbuf; gq.out[2] = vtb;
  gq.modes = (1 << 4);                         // z0,z1: bf16; z2: Vt
  gemm_mfma<4><<<dim3(16, 32, 3), 256, 0, stream>>>(gq);

  rope_kernel<<<dim3(2048, 2), 256, 0, stream>>>(qbuf, kbuf, tp);

  attn_mfma<<<dim3(16, 32), 512, 0, stream>>>(qbuf, kbuf, vtb, abuf);

  GemmArgs go;
  go.A = abuf;
  go.W[0] = wob; go.W[1] = wob; go.W[2] = wob;
  go.out[0] = out; go.out[1] = out; go.out[2] = out;
  go.modes = 2;                                // fp32 out
  gemm_mfma<4><<<dim3(16, 32, 1), 256, 0, stream>>>(go);
}